// Round 8
// baseline (193.915 us; speedup 1.0000x reference)
//
#include <hip/hip_runtime.h>
#include <hip/hip_bf16.h>
#include <stdint.h>

#define DEV __device__ __forceinline__

typedef short short8 __attribute__((ext_vector_type(8)));
typedef float floatx4 __attribute__((ext_vector_type(4)));
typedef uint32_t uint32x4 __attribute__((ext_vector_type(4)));

constexpr int D = 256;
constexpr int NTOK = 8192;
constexpr int MTOT = 4 * NTOK;  // 32768 rows total
constexpr int W_E = D * D;

DEV void gl_lds16(const void* g, void* l) {
  __builtin_amdgcn_global_load_lds(
      (const __attribute__((address_space(1))) void*)g,
      (__attribute__((address_space(3))) void*)l, 16, 0, 0);
}

DEV float bflo(uint32_t u) { return __uint_as_float(u << 16); }
DEV float bfhi(uint32_t u) { return __uint_as_float(u & 0xffff0000u); }
DEV uint32_t packbf(float a, float b) {
  uint16_t xa = __builtin_bit_cast(uint16_t, __float2bfloat16(a));
  uint16_t xb = __builtin_bit_cast(uint16_t, __float2bfloat16(b));
  return (uint32_t)xa | ((uint32_t)xb << 16);
}

// ---------------- Kernel 1: fused QKV GEMM, fp32 inputs staged inline as bf16 ---------------
// grid (3, 256): x = mat (0=Q,1=K,2=V), y = m-block. Fuses bias, Q-rotary, and K/V
// w-weighted column-norm PARTIALS (plain stores to ns_part[mat-1][b][128][256]).
__global__ __launch_bounds__(256, 2) void gemm_qkv(
    const float* __restrict__ phi, const float* __restrict__ Wq,
    const float* __restrict__ Wk, const float* __restrict__ Wv,
    const float* __restrict__ bq, const float* __restrict__ bk, const float* __restrict__ bv,
    const float* __restrict__ coords, const float* __restrict__ wts,
    const float* __restrict__ lift,
    __hip_bfloat16* __restrict__ Qb, __hip_bfloat16* __restrict__ Kb,
    __hip_bfloat16* __restrict__ Vb, float* __restrict__ ns_part) {
  __shared__ __align__(16) char As[8192];    // 128 rows x 64B (32 bf16 k-slice)
  __shared__ __align__(16) char Bs[16384];   // 256 rows x 64B
  const int t = threadIdx.x, lane = t & 63, wid = t >> 6;
  const int wm = (wid & 1) * 64, wn = (wid >> 1) * 64;
  const int l16 = lane & 15, q4 = lane >> 4;
  const int mat = blockIdx.x;
  const int m0 = blockIdx.y * 128;
  const float* Wsel = (mat == 0) ? Wq : (mat == 1) ? Wk : Wv;
  const float* bias = (mat == 0) ? bq : (mat == 1) ? bk : bv;
  __hip_bfloat16* Out = (mat == 0) ? Qb : (mat == 1) ? Kb : Vb;

  floatx4 acc[4][8] = {};

  const int srow = wid * 16 + (lane >> 2);   // 0..63
  const int skoff = (lane & 3) * 8;          // element offset within 32-wide k slice
  const float* pa = phi + (size_t)(m0 + srow) * D + skoff;
  const float* pw = Wsel + (size_t)srow * D + skoff;
  char* lA = As + srow * 64 + skoff * 2;
  char* lB = Bs + srow * 64 + skoff * 2;

  for (int kt = 0; kt < 256; kt += 32) {
    const float4 a0 = *(const float4*)(pa + kt);
    const float4 a1 = *(const float4*)(pa + kt + 4);
    const float4 a2 = *(const float4*)(pa + kt + 64 * D);
    const float4 a3 = *(const float4*)(pa + kt + 64 * D + 4);
    const float4 w0 = *(const float4*)(pw + kt);
    const float4 w1 = *(const float4*)(pw + kt + 4);
    const float4 w2 = *(const float4*)(pw + kt + 64 * D);
    const float4 w3 = *(const float4*)(pw + kt + 64 * D + 4);
    const float4 w4 = *(const float4*)(pw + kt + 128 * D);
    const float4 w5 = *(const float4*)(pw + kt + 128 * D + 4);
    const float4 w6 = *(const float4*)(pw + kt + 192 * D);
    const float4 w7 = *(const float4*)(pw + kt + 192 * D + 4);
    uint32x4 uA0, uA1, uB0, uB1, uB2, uB3;
    uA0[0] = packbf(a0.x, a0.y); uA0[1] = packbf(a0.z, a0.w);
    uA0[2] = packbf(a1.x, a1.y); uA0[3] = packbf(a1.z, a1.w);
    uA1[0] = packbf(a2.x, a2.y); uA1[1] = packbf(a2.z, a2.w);
    uA1[2] = packbf(a3.x, a3.y); uA1[3] = packbf(a3.z, a3.w);
    uB0[0] = packbf(w0.x, w0.y); uB0[1] = packbf(w0.z, w0.w);
    uB0[2] = packbf(w1.x, w1.y); uB0[3] = packbf(w1.z, w1.w);
    uB1[0] = packbf(w2.x, w2.y); uB1[1] = packbf(w2.z, w2.w);
    uB1[2] = packbf(w3.x, w3.y); uB1[3] = packbf(w3.z, w3.w);
    uB2[0] = packbf(w4.x, w4.y); uB2[1] = packbf(w4.z, w4.w);
    uB2[2] = packbf(w5.x, w5.y); uB2[3] = packbf(w5.z, w5.w);
    uB3[0] = packbf(w6.x, w6.y); uB3[1] = packbf(w6.z, w6.w);
    uB3[2] = packbf(w7.x, w7.y); uB3[3] = packbf(w7.z, w7.w);
    *(uint32x4*)lA = uA0;
    *(uint32x4*)(lA + 4096) = uA1;
    *(uint32x4*)lB = uB0;
    *(uint32x4*)(lB + 4096) = uB1;
    *(uint32x4*)(lB + 8192) = uB2;
    *(uint32x4*)(lB + 12288) = uB3;
    __syncthreads();
    short8 af[4], bf8[8];
#pragma unroll
    for (int i = 0; i < 4; i++)
      af[i] = *(const short8*)(As + (wm + i * 16 + l16) * 64 + q4 * 16);
#pragma unroll
    for (int j = 0; j < 8; j++) {
      const int col = wn + (j & 3) * 16 + (j >> 2) * 128 + l16;
      bf8[j] = *(const short8*)(Bs + col * 64 + q4 * 16);
    }
#pragma unroll
    for (int i = 0; i < 4; i++)
#pragma unroll
      for (int j = 0; j < 8; j++)
        acc[i][j] = __builtin_amdgcn_mfma_f32_16x16x32_bf16(af[i], bf8[j], acc[i][j], 0, 0, 0);
    __syncthreads();
  }

  float bcol[8];
#pragma unroll
  for (int j = 0; j < 8; j++)
    bcol[j] = bias[wn + (j & 3) * 16 + (j >> 2) * 128 + l16];

  if (mat == 0) {
    float lx[4], ly[4], lz[4];
#pragma unroll
    for (int c4 = 0; c4 < 4; c4++) {
      const int c = wn + c4 * 16 + l16;
      lx[c4] = lift[c * 3 + 0]; ly[c4] = lift[c * 3 + 1]; lz[c4] = lift[c * 3 + 2];
    }
#pragma unroll
    for (int i = 0; i < 4; i++) {
#pragma unroll
      for (int r = 0; r < 4; r++) {
        const int row = m0 + wm + i * 16 + q4 * 4 + r;
        const float cx = coords[row * 3 + 0];
        const float cy = coords[row * 3 + 1];
        const float cz = coords[row * 3 + 2];
#pragma unroll
        for (int c4 = 0; c4 < 4; c4++) {
          const int c = wn + c4 * 16 + l16;
          const float p = cx * lx[c4] + cy * ly[c4] + cz * lz[c4];
          float s, cs;
          __sincosf(p, &s, &cs);
          const float f1 = acc[i][c4][r] + bcol[c4];
          const float f2 = acc[i][c4 + 4][r] + bcol[c4 + 4];
          Out[(size_t)row * D + c]       = __float2bfloat16(f1 * cs - f2 * s);
          Out[(size_t)row * D + c + 128] = __float2bfloat16(f1 * s + f2 * cs);
        }
      }
    }
  } else {
    const int b = m0 >> 13;
    const int mb2 = ((blockIdx.y & 63) << 1) | (wid & 1);
    float* ns = ns_part + (((size_t)(mat - 1) * 4 + b) * 128 + mb2) * 256;
    float colsum[8] = {};
#pragma unroll
    for (int i = 0; i < 4; i++) {
#pragma unroll
      for (int r = 0; r < 4; r++) {
        const int row = m0 + wm + i * 16 + q4 * 4 + r;
        const float w = wts[row];
#pragma unroll
        for (int j = 0; j < 8; j++) {
          const int col = wn + (j & 3) * 16 + (j >> 2) * 128 + l16;
          const float psi = acc[i][j][r] + bcol[j];
          Out[(size_t)row * D + col] = __float2bfloat16(psi);
          colsum[j] += w * psi * psi;
        }
      }
    }
#pragma unroll
    for (int j = 0; j < 8; j++) {
      float s = colsum[j];
      s += __shfl_xor(s, 16);
      s += __shfl_xor(s, 32);
      if (q4 == 0) {
        const int col = wn + (j & 3) * 16 + (j >> 2) * 128 + l16;
        ns[col] = s;  // per-(mblock, warp-pair) partial, plain store
      }
    }
  }
}

// ---------------- Kernel 2: fused vproj-GEMM + K-pointwise (grid fusion) --------------------
// blocks [0,512): vproj = Vraw @ (Wo*rsqrt(nsv))^T; nsv reduced from ns_part at phase start.
// blocks [512,640): K pointwise basis_norm -> rotary -> *w (nsk reduced into LDS first).
__global__ __launch_bounds__(256, 2) void vproj_pk(
    const __hip_bfloat16* __restrict__ Vb, const float* __restrict__ Wo,
    const float* __restrict__ ns_part, __hip_bfloat16* __restrict__ vproj,
    __hip_bfloat16* __restrict__ Kb, const float* __restrict__ coords,
    const float* __restrict__ wts, const float* __restrict__ lift) {
  __shared__ __align__(16) char smem[17408];  // As 8K | Bs 8K | isv 1K
  const int bx = blockIdx.x;
  const int t = threadIdx.x;

  if (bx < 512) {
    char* As = smem;
    char* Bs = smem + 8192;
    float* isv = (float*)(smem + 16384);
    const int lane = t & 63, wid = t >> 6;
    const int wm = (wid & 1) * 64, wn = (wid >> 1) * 64;
    const int l16 = lane & 15, q4 = lane >> 4;
    const int m0 = (bx >> 1) * 128, n0 = (bx & 1) * 128;
    const int b = m0 >> 13;
    {
      const float* np = ns_part + ((size_t)(4 + b) * 128) * 256;  // mat=V -> idx 1
      float s = 1e-5f;
      for (int r = 0; r < 128; r++) s += np[r * 256 + t];
      isv[t] = rsqrtf(s);
    }
    __syncthreads();
    floatx4 acc[4][4] = {};
    const int srow = wid * 16 + (lane >> 2);
    const int skoff = (lane & 3) * 8;
    const __hip_bfloat16* gA = Vb + (size_t)(m0 + srow) * D + skoff;
    const float* gB0 = Wo + (size_t)(n0 + srow) * D + skoff;
    const float* gB1 = Wo + (size_t)(n0 + srow + 64) * D + skoff;
    char* lA = As + srow * 64 + skoff * 2;
    char* lB = Bs + srow * 64 + skoff * 2;
    for (int kt = 0; kt < 256; kt += 32) {
      gl_lds16(gA + kt, lA);
      gl_lds16(gA + kt + 64 * D, lA + 4096);
      const float4 w0 = *(const float4*)(gB0 + kt);
      const float4 w1 = *(const float4*)(gB0 + kt + 4);
      const float4 w2 = *(const float4*)(gB1 + kt);
      const float4 w3 = *(const float4*)(gB1 + kt + 4);
      const float4 i0 = *(const float4*)(&isv[kt + skoff]);
      const float4 i1 = *(const float4*)(&isv[kt + skoff + 4]);
      uint32x4 p0, p1;
      p0[0] = packbf(w0.x * i0.x, w0.y * i0.y);
      p0[1] = packbf(w0.z * i0.z, w0.w * i0.w);
      p0[2] = packbf(w1.x * i1.x, w1.y * i1.y);
      p0[3] = packbf(w1.z * i1.z, w1.w * i1.w);
      p1[0] = packbf(w2.x * i0.x, w2.y * i0.y);
      p1[1] = packbf(w2.z * i0.z, w2.w * i0.w);
      p1[2] = packbf(w3.x * i1.x, w3.y * i1.y);
      p1[3] = packbf(w3.z * i1.z, w3.w * i1.w);
      *(uint32x4*)lB = p0;
      *(uint32x4*)(lB + 4096) = p1;
      __syncthreads();
      short8 af[4], bf8[4];
#pragma unroll
      for (int i = 0; i < 4; i++) {
        af[i]  = *(const short8*)(As + (wm + i * 16 + l16) * 64 + q4 * 16);
        bf8[i] = *(const short8*)(Bs + (wn + i * 16 + l16) * 64 + q4 * 16);
      }
#pragma unroll
      for (int i = 0; i < 4; i++)
#pragma unroll
        for (int j = 0; j < 4; j++)
          acc[i][j] = __builtin_amdgcn_mfma_f32_16x16x32_bf16(af[i], bf8[j], acc[i][j], 0, 0, 0);
      __syncthreads();
    }
#pragma unroll
    for (int j = 0; j < 4; j++) {
      const int colg = n0 + wn + j * 16 + l16;
#pragma unroll
      for (int i = 0; i < 4; i++) {
        const int rowg = m0 + wm + i * 16 + q4 * 4;
#pragma unroll
        for (int r = 0; r < 4; r++)
          vproj[(size_t)(rowg + r) * D + colg] = __float2bfloat16(acc[i][j][r]);
      }
    }
  } else {
    // ---- K pointwise: 256 rows per block ----
    float* snk = (float*)smem;  // 256 inverse norms
    const int pb = bx - 512;
    const int r0 = pb * 256;
    const int b = r0 >> 13;
    {
      const float* np = ns_part + ((size_t)(0 + b) * 128) * 256;  // mat=K -> idx 0
      float s = 1e-5f;
      for (int r = 0; r < 128; r++) s += np[r * 256 + t];
      snk[t] = rsqrtf(s);
    }
    __syncthreads();
    const int j = t & 63, rloc = t >> 6;
    const int j0 = 2 * j, j1 = 2 * j + 1;
    const float lx0 = lift[j0 * 3 + 0], ly0 = lift[j0 * 3 + 1], lz0 = lift[j0 * 3 + 2];
    const float lx1 = lift[j1 * 3 + 0], ly1 = lift[j1 * 3 + 1], lz1 = lift[j1 * 3 + 2];
    const float ik0 = snk[j0], ik1 = snk[j1];
    const float ik2 = snk[128 + j0], ik3 = snk[128 + j1];
    uint32_t* K32 = (uint32_t*)Kb;
    for (int it = 0; it < 64; it++) {
      const size_t row = (size_t)r0 + it * 4 + rloc;
      const float cx = coords[row * 3 + 0];
      const float cy = coords[row * 3 + 1];
      const float cz = coords[row * 3 + 2];
      const float p0 = cx * lx0 + cy * ly0 + cz * lz0;
      const float p1 = cx * lx1 + cy * ly1 + cz * lz1;
      float s0, c0, s1, c1;
      __sincosf(p0, &s0, &c0);
      __sincosf(p1, &s1, &c1);
      const float w = wts[row];
      const size_t base = row * 128;
      const uint32_t klo = K32[base + j], khi = K32[base + 64 + j];
      const float k1a = bflo(klo) * ik0, k1b = bfhi(klo) * ik1;
      const float k2a = bflo(khi) * ik2, k2b = bfhi(khi) * ik3;
      K32[base + j]      = packbf((k1a * c0 - k2a * s0) * w, (k1b * c1 - k2b * s1) * w);
      K32[base + 64 + j] = packbf((k1a * s0 + k2a * c0) * w, (k1b * s1 + k2b * c1) * w);
    }
  }
}

// ---------------- Kernel 3: part[chunk][b] partial KVt, transposed-LDS MFMA, bf16 out -------
__global__ __launch_bounds__(256, 2) void gemm_tn(
    const __hip_bfloat16* __restrict__ Vp, const __hip_bfloat16* __restrict__ Kwb,
    __hip_bfloat16* __restrict__ part) {
  __shared__ __align__(16) char Asm[128 * 80];
  __shared__ __align__(16) char Bsm[128 * 80];
  const int t = threadIdx.x, lane = t & 63, wid = t >> 6;
  const int wm = (wid & 1) * 64, wn = (wid >> 1) * 64;
  const int l16 = lane & 15, q4 = lane >> 4;
  const int chunk = blockIdx.x, ed = blockIdx.y, b = blockIdx.z;
  const int e0 = (ed & 1) * 128, d0 = (ed >> 1) * 128;
  const uint32_t* V32 = (const uint32_t*)Vp;
  const uint32_t* K32 = (const uint32_t*)Kwb;
  const int s_np = (((t & 3) | ((t >> 6) << 2)) ^ ((t >> 4) & 3));  // 0..15
  const int s_e2lo = (t >> 2) & 15;
  floatx4 acc[4][4] = {};
  for (int nt = 0; nt < 256; nt += 32) {
    const int nbase = chunk * 256 + nt;
    const size_t tokbase = ((size_t)b * NTOK + nbase + 2 * s_np) * 128;
#pragma unroll
    for (int r = 0; r < 4; r++) {
      const int e2 = s_e2lo + r * 16;
      {
        const uint32_t a0 = V32[tokbase + (e0 >> 1) + e2];
        const uint32_t a1 = V32[tokbase + 128 + (e0 >> 1) + e2];
        *(uint32_t*)(Asm + (2 * e2) * 80 + 4 * s_np)     = (a0 & 0xffffu) | (a1 << 16);
        *(uint32_t*)(Asm + (2 * e2 + 1) * 80 + 4 * s_np) = (a0 >> 16) | (a1 & 0xffff0000u);
      }
      {
        const uint32_t b0 = K32[tokbase + (d0 >> 1) + e2];
        const uint32_t b1 = K32[tokbase + 128 + (d0 >> 1) + e2];
        *(uint32_t*)(Bsm + (2 * e2) * 80 + 4 * s_np)     = (b0 & 0xffffu) | (b1 << 16);
        *(uint32_t*)(Bsm + (2 * e2 + 1) * 80 + 4 * s_np) = (b0 >> 16) | (b1 & 0xffff0000u);
      }
    }
    __syncthreads();
    short8 af[4], bf8[4];
#pragma unroll
    for (int i = 0; i < 4; i++) {
      af[i]  = *(const short8*)(Asm + (wm + i * 16 + l16) * 80 + q4 * 16);
      bf8[i] = *(const short8*)(Bsm + (wn + i * 16 + l16) * 80 + q4 * 16);
    }
#pragma unroll
    for (int i = 0; i < 4; i++)
#pragma unroll
      for (int j = 0; j < 4; j++)
        acc[i][j] = __builtin_amdgcn_mfma_f32_16x16x32_bf16(af[i], bf8[j], acc[i][j], 0, 0, 0);
    __syncthreads();
  }
  __hip_bfloat16* pt = part + (((size_t)(chunk * 4 + b)) << 16);
#pragma unroll
  for (int i = 0; i < 4; i++) {
#pragma unroll
    for (int r = 0; r < 4; r++) {
      const int eg = e0 + wm + i * 16 + q4 * 4 + r;
#pragma unroll
      for (int j = 0; j < 4; j++) {
        const int dg = d0 + wn + j * 16 + l16;
        pt[eg * 256 + dg] = __float2bfloat16(acc[i][j][r]);
      }
    }
  }
}

// ---------------- Kernel 4: P[b] = bf16( sum_chunks part[chunk][b] ) ------------------------
__global__ __launch_bounds__(256) void reduce_kvt(const uint32_t* __restrict__ part,
                                                  uint32_t* __restrict__ P) {
  const int flat2 = blockIdx.x * 256 + threadIdx.x;
  const int b = flat2 >> 15;
  const int off = flat2 & 32767;
  float sx = 0, sy = 0;
#pragma unroll
  for (int c = 0; c < 32; c++) {
    const uint32_t u = part[(((size_t)(c * 4 + b)) << 15) + off];
    sx += bflo(u); sy += bfhi(u);
  }
  P[flat2] = packbf(sx, sy);
}

// ---------------- Kernel 5: out = q_rot @ P^T + bo  (fp32 out to d_out) ---------------------
__global__ __launch_bounds__(256, 2) void gemm_out(
    const __hip_bfloat16* __restrict__ A, const __hip_bfloat16* __restrict__ Pm,
    const float* __restrict__ bo, float* __restrict__ Og) {
  __shared__ __align__(16) char As[8192];
  __shared__ __align__(16) char Bs[8192];
  const int t = threadIdx.x, lane = t & 63, wid = t >> 6;
  const int wm = (wid & 1) * 64, wn = (wid >> 1) * 64;
  const int l16 = lane & 15, q4 = lane >> 4;
  const int m0 = blockIdx.x * 128, n0 = blockIdx.y * 128;
  const int b = m0 >> 13;
  const __hip_bfloat16* W = Pm + ((size_t)b << 16);
  floatx4 acc[4][4] = {};
  const int srow = wid * 16 + (lane >> 2);
  const int skoff = (lane & 3) * 8;
  const __hip_bfloat16* gA = A + (size_t)(m0 + srow) * D + skoff;
  const __hip_bfloat16* gB = W + (size_t)(n0 + srow) * D + skoff;
  char* lA = As + srow * 64 + skoff * 2;
  char* lB = Bs + srow * 64 + skoff * 2;
  for (int kt = 0; kt < 256; kt += 32) {
    gl_lds16(gA + kt, lA);
    gl_lds16(gA + kt + 64 * D, lA + 4096);
    gl_lds16(gB + kt, lB);
    gl_lds16(gB + kt + 64 * D, lB + 4096);
    __syncthreads();
    short8 af[4], bf8[4];
#pragma unroll
    for (int i = 0; i < 4; i++) {
      af[i]  = *(const short8*)(As + (wm + i * 16 + l16) * 64 + q4 * 16);
      bf8[i] = *(const short8*)(Bs + (wn + i * 16 + l16) * 64 + q4 * 16);
    }
#pragma unroll
    for (int i = 0; i < 4; i++)
#pragma unroll
      for (int j = 0; j < 4; j++)
        acc[i][j] = __builtin_amdgcn_mfma_f32_16x16x32_bf16(af[i], bf8[j], acc[i][j], 0, 0, 0);
    __syncthreads();
  }
#pragma unroll
  for (int j = 0; j < 4; j++) {
    const int colg = n0 + wn + j * 16 + l16;
    const float bb = bo[colg];
#pragma unroll
    for (int i = 0; i < 4; i++) {
      const int rowg = m0 + wm + i * 16 + q4 * 4;
#pragma unroll
      for (int r = 0; r < 4; r++)
        Og[(size_t)(rowg + r) * D + colg] = acc[i][j][r] + bb;
    }
  }
}

extern "C" void kernel_launch(void* const* d_in, const int* in_sizes, int n_in,
                              void* d_out, int out_size, void* d_ws, size_t ws_size,
                              hipStream_t stream) {
  const float* phi    = (const float*)d_in[0];
  const float* coords = (const float*)d_in[1];
  const float* wts    = (const float*)d_in[2];
  const float* Wq     = (const float*)d_in[3];
  const float* bq     = (const float*)d_in[4];
  const float* Wk     = (const float*)d_in[5];
  const float* bk     = (const float*)d_in[6];
  const float* Wv     = (const float*)d_in[7];
  const float* bv     = (const float*)d_in[8];
  const float* Wo     = (const float*)d_in[9];
  const float* bo     = (const float*)d_in[10];
  const float* lift   = (const float*)d_in[11];

  char* ws = (char*)d_ws;
  const size_t SZ = (size_t)MTOT * D * 2;  // 16 MiB per bf16 token buffer
  __hip_bfloat16* Qb = (__hip_bfloat16*)ws;
  __hip_bfloat16* Kb = (__hip_bfloat16*)(ws + SZ);
  __hip_bfloat16* Vb = (__hip_bfloat16*)(ws + 2 * SZ);
  float* ns_part = (float*)(ws + 3 * SZ);                                // 1 MiB
  __hip_bfloat16* part  = (__hip_bfloat16*)(ws + 3 * SZ + 1048576);      // 16 MiB
  __hip_bfloat16* Pm    = (__hip_bfloat16*)(ws + 4 * SZ + 1048576);      // 512 KiB
  __hip_bfloat16* vproj = (__hip_bfloat16*)(ws + 4 * SZ + 1048576 + 524288);

  gemm_qkv<<<dim3(3, 256), 256, 0, stream>>>(phi, Wq, Wk, Wv, bq, bk, bv, coords, wts, lift,
                                             Qb, Kb, Vb, ns_part);
  vproj_pk<<<640, 256, 0, stream>>>(Vb, Wo, ns_part, vproj, Kb, coords, wts, lift);
  gemm_tn<<<dim3(32, 4, 4), 256, 0, stream>>>(vproj, Kb, part);
  reduce_kvt<<<512, 256, 0, stream>>>((const uint32_t*)part, (uint32_t*)Pm);
  gemm_out<<<dim3(256, 2), 256, 0, stream>>>(Qb, Pm, bo, (float*)d_out);
}